// Round 10
// baseline (88.654 us; speedup 1.0000x reference)
//
#include <hip/hip_runtime.h>
#include <math.h>

// Problem constants: B=64, D=512, H=W=32 -> N=1024, NH=8, DH=64
#define BATCH  64
#define DCH    512
#define NPOS   1024
#define NH     8
#define NSPLIT 16
#define NRANGE 64
#define SCL    0.1803368801111244f   // 0.125 * log2(e): scores in exp2 domain

// ---------------------------------------------------------------------------
// K1 (prep): blocks 0-1: wqT[c*8+h] = SCL * sum_d q[h,d]*Wkv[c,h*64+d]
//            blocks 2-5: bias[h*1024+n] = SCL*(q.pe[n] + q.bkv)
// ---------------------------------------------------------------------------
__global__ __launch_bounds__(256) void k_prep(const float* __restrict__ q,
                                              const float* __restrict__ Wkv,
                                              const float* __restrict__ bkv,
                                              float* __restrict__ wqT,
                                              float* __restrict__ bias) {
    int blk = blockIdx.x;
    if (blk < 2) {
        int c = blk * 256 + threadIdx.x;
        const float4* wrow = (const float4*)(Wkv + (size_t)c * (2 * DCH));
        const float4* q4   = (const float4*)q;
        #pragma unroll
        for (int h = 0; h < NH; ++h) {
            float s = 0.f;
            #pragma unroll
            for (int d4 = 0; d4 < 16; ++d4) {
                float4 a = q4[h * 16 + d4];
                float4 w = wrow[h * 16 + d4];
                s = fmaf(a.x, w.x, fmaf(a.y, w.y, fmaf(a.z, w.z, fmaf(a.w, w.w, s))));
            }
            wqT[c * NH + h] = SCL * s;
        }
    } else {
        int n = (blk - 2) * 256 + threadIdx.x;
        float pq[NH];
        #pragma unroll
        for (int h = 0; h < NH; ++h) pq[h] = 0.f;
        const float kfac2 = -13.2877123795494f / 64.f;   // -log2(10000)/64
        for (int i = 0; i < 32; ++i) {
            float dt = exp2f((float)(2 * i) * kfac2);
            float ang = (float)n * dt;
            float sn, cs;
            sincosf(ang, &sn, &cs);
            #pragma unroll
            for (int h = 0; h < NH; ++h)
                pq[h] = fmaf(q[h * 64 + 2 * i], sn,
                        fmaf(q[h * 64 + 2 * i + 1], cs, pq[h]));
        }
        #pragma unroll
        for (int h = 0; h < NH; ++h) {
            float bq = 0.f;
            #pragma unroll 8
            for (int d = 0; d < 64; ++d)
                bq = fmaf(q[h * 64 + d], bkv[h * 64 + d], bq);
            bias[h * NPOS + n] = SCL * (pq[h] + bq);
        }
    }
}

// ---------------------------------------------------------------------------
// K2 (flash): grid (NSPLIT=16, B) = 1024 blocks, 512 threads.
//  phase 1: rg=lane>>4, n4=lane&15; rolling 8-deep float4 load window over
//           16 rows/thread; weights broadcast from LDS (2 b128/row).
//  prefetch: phase-3 j=0 x-loads issued BEFORE sync1 (latency overlaps
//           barrier + softmax + barrier).
//  phase 2: wave h = head h, in-wave softmax over the 64-n tile (exp2).
//  phase 3: rg3=lane>>2, nq=lane&3; double-buffered j-loop; p broadcast
//           from LDS; quad xor1/xor2 reduce; x re-read hits L2/L3.
// ---------------------------------------------------------------------------
__global__ __launch_bounds__(512, 4) void k_flash(const float* __restrict__ x,
                                                  const float* __restrict__ wqT,
                                                  const float* __restrict__ bias,
                                                  float* __restrict__ apart,  // [NSPLIT][B][NH][DCH]
                                                  float* __restrict__ mz) {   // [NSPLIT][B][16]
    __shared__ float wqs[DCH * NH];        // 16 KB
    __shared__ float sred[8][NH][NRANGE];  // 16 KB
    __shared__ float pbuf[NH][NRANGE];     // 2 KB

    int b = blockIdx.y, ns = blockIdx.x;
    int t = threadIdx.x;
    int w = t >> 6;
    int lane = t & 63;
    int n0 = ns * NRANGE;
    int c0 = w * 64;

    {   // stage wq -> LDS (coalesced)
        const float4* s = (const float4*)wqT;
        float4* d = (float4*)wqs;
        d[t] = s[t]; d[t + 512] = s[t + 512];
    }
    __syncthreads();

    // ---------------- phase 1: dots, rolling 8-deep window ----------------
    int rg = lane >> 4;      // 4 row-groups
    int n4 = lane & 15;      // 16 n-quads
    const float* gx = x + ((size_t)b * DCH + c0 + rg) * NPOS + n0 + n4 * 4;

    float acc[NH][4];
    #pragma unroll
    for (int h = 0; h < NH; ++h)
        #pragma unroll
        for (int e = 0; e < 4; ++e) acc[h][e] = 0.f;

    float4 xw[8];
    #pragma unroll
    for (int k = 0; k < 8; ++k)
        xw[k] = *(const float4*)(gx + (size_t)(4 * k) * NPOS);

    #pragma unroll
    for (int k = 0; k < 16; ++k) {
        float4 xv = xw[k & 7];
        if (k < 8)   // refill slot with row k+8 -> constant 8 in flight
            xw[k & 7] = *(const float4*)(gx + (size_t)(4 * (k + 8)) * NPOS);
        int c = c0 + 4 * k + rg;
        float wv[8];
        *(float4*)&wv[0] = *(const float4*)&wqs[c * 8];
        *(float4*)&wv[4] = *(const float4*)&wqs[c * 8 + 4];
        #pragma unroll
        for (int h = 0; h < NH; ++h) {
            acc[h][0] = fmaf(xv.x, wv[h], acc[h][0]);
            acc[h][1] = fmaf(xv.y, wv[h], acc[h][1]);
            acc[h][2] = fmaf(xv.z, wv[h], acc[h][2]);
            acc[h][3] = fmaf(xv.w, wv[h], acc[h][3]);
        }
    }
    // reduce across the 4 row-groups (lane bits 4,5)
    #pragma unroll
    for (int h = 0; h < NH; ++h)
        #pragma unroll
        for (int e = 0; e < 4; ++e) {
            float v = acc[h][e];
            v += __shfl_xor(v, 16);
            v += __shfl_xor(v, 32);
            acc[h][e] = v;
        }
    if (rg == 0) {
        #pragma unroll
        for (int h = 0; h < NH; ++h)
            *(float4*)&sred[w][h][n4 * 4] =
                make_float4(acc[h][0], acc[h][1], acc[h][2], acc[h][3]);
    }

    // ---- phase-3 j=0 prefetch (issued BEFORE the barrier) ----
    int rg3 = lane >> 2;   // 16 rows
    int nq  = lane & 3;    // 4 n-quads
    const float* xr = x + ((size_t)b * DCH + c0 + rg3) * NPOS + n0 + nq * 4;
    float4 xcur[4];
    #pragma unroll
    for (int cp = 0; cp < 4; ++cp)
        xcur[cp] = *(const float4*)(xr + (size_t)(cp * 16) * NPOS);

    __syncthreads();

    // ---------------- phase 2: softmax (wave w = head w, exp2) -------------
    {
        float s = bias[w * NPOS + n0 + lane];
        #pragma unroll
        for (int o = 0; o < 8; ++o) s += sred[o][w][lane];
        float m = s;
        #pragma unroll
        for (int o = 32; o; o >>= 1) m = fmaxf(m, __shfl_xor(m, o));
        float p = exp2f(s - m);
        float z = p;
        #pragma unroll
        for (int o = 32; o; o >>= 1) z += __shfl_xor(z, o);
        pbuf[w][lane] = p;
        if (lane == 0) {
            float* mzp = mz + ((size_t)ns * BATCH + b) * 2 * NH;
            mzp[w]      = m;     // exp2-domain max
            mzp[NH + w] = z;
        }
    }
    __syncthreads();

    // ---------------- phase 3: PV, double-buffered j-loop ----------------
    {
        float con[4][NH];
        #pragma unroll
        for (int cp = 0; cp < 4; ++cp)
            #pragma unroll
            for (int h = 0; h < NH; ++h) con[cp][h] = 0.f;

        #pragma unroll
        for (int j = 0; j < 4; ++j) {
            float4 xnx[4];
            if (j < 3) {
                #pragma unroll
                for (int cp = 0; cp < 4; ++cp)
                    xnx[cp] = *(const float4*)(xr + (size_t)(cp * 16) * NPOS + (j + 1) * 16);
            }
            float4 pj[NH];
            #pragma unroll
            for (int h = 0; h < NH; ++h)
                pj[h] = *(const float4*)&pbuf[h][j * 16 + nq * 4];
            #pragma unroll
            for (int cp = 0; cp < 4; ++cp)
                #pragma unroll
                for (int h = 0; h < NH; ++h)
                    con[cp][h] = fmaf(xcur[cp].x, pj[h].x, fmaf(xcur[cp].y, pj[h].y,
                                 fmaf(xcur[cp].z, pj[h].z, fmaf(xcur[cp].w, pj[h].w, con[cp][h]))));
            if (j < 3) {
                #pragma unroll
                for (int cp = 0; cp < 4; ++cp) xcur[cp] = xnx[cp];
            }
        }

        // reduce over nq (xor1, xor2) and store
        #pragma unroll
        for (int cp = 0; cp < 4; ++cp)
            #pragma unroll
            for (int h = 0; h < NH; ++h) {
                float v = con[cp][h];
                v += __shfl_xor(v, 1);
                v += __shfl_xor(v, 2);
                con[cp][h] = v;
            }

        size_t abase = ((size_t)ns * BATCH + b) * (NH * DCH);
        #pragma unroll
        for (int cp = 0; cp < 4; ++cp) {
            int c = c0 + cp * 16 + rg3;
            float lo = (nq == 0) ? con[cp][0] : (nq == 1) ? con[cp][1]
                     : (nq == 2) ? con[cp][2] : con[cp][3];
            float hi = (nq == 0) ? con[cp][4] : (nq == 1) ? con[cp][5]
                     : (nq == 2) ? con[cp][6] : con[cp][7];
            apart[abase + (size_t)nq * DCH + c]       = lo;
            apart[abase + (size_t)(nq + 4) * DCH + c] = hi;
        }
    }
}

// ---------------------------------------------------------------------------
// K3: combine NSPLIT partials + output GEMV. grid (B, 2), 512 threads.
// Each half-block touches only its own 4 heads (half the apart traffic).
// ---------------------------------------------------------------------------
__global__ __launch_bounds__(512) void k_comb(const float* __restrict__ apart,
                                              const float* __restrict__ mz,
                                              const float* __restrict__ Wkv,
                                              const float* __restrict__ bkv,
                                              float* __restrict__ out) {
    __shared__ float as[2048];       // 4 heads x 512 c (this half)
    __shared__ float red[2][256];
    int b = blockIdx.x, half = blockIdx.y, t = threadIdx.x;

    int e0 = t * 4;                          // local [0,2048)
    int h  = half * 4 + (t >> 7);            // global head of this thread's 4 elems

    float M = -1e30f;
    #pragma unroll
    for (int j = 0; j < NSPLIT; ++j)
        M = fmaxf(M, mz[((size_t)j * BATCH + b) * 2 * NH + h]);
    float Z = 0.f, fj[NSPLIT];
    #pragma unroll
    for (int j = 0; j < NSPLIT; ++j) {
        const float* mzp = mz + ((size_t)j * BATCH + b) * 2 * NH;
        fj[j] = exp2f(mzp[h] - M);
        Z = fmaf(fj[j], mzp[NH + h], Z);
    }
    float invZ = 1.f / Z;

    float v0 = 0.f, v1 = 0.f, v2 = 0.f, v3 = 0.f;
    #pragma unroll 4
    for (int j = 0; j < NSPLIT; ++j) {
        const float* src = apart + ((size_t)j * BATCH + b) * (NH * DCH)
                         + half * 2048 + e0;
        float4 lo = *(const float4*)src;
        v0 = fmaf(fj[j], lo.x, v0);
        v1 = fmaf(fj[j], lo.y, v1);
        v2 = fmaf(fj[j], lo.z, v2);
        v3 = fmaf(fj[j], lo.w, v3);
    }
    as[e0]     = v0 * invZ;
    as[e0 + 1] = v1 * invZ;
    as[e0 + 2] = v2 * invZ;
    as[e0 + 3] = v3 * invZ;
    __syncthreads();

    int o  = t & 255;
    int cp = t >> 8;
    int hd = half * 256 + o;                 // output column
    float a0 = 0.f, a1 = 0.f, a2 = 0.f, a3 = 0.f;
    const float* wp  = Wkv + DCH + hd;
    const float* apr = as + (o >> 6) * DCH;  // local head = o>>6
    int cbeg = cp * 256;
    #pragma unroll 4
    for (int c = cbeg; c < cbeg + 256; c += 4) {
        a0 = fmaf(apr[c],     wp[(size_t)c * (2 * DCH)],       a0);
        a1 = fmaf(apr[c + 1], wp[(size_t)(c + 1) * (2 * DCH)], a1);
        a2 = fmaf(apr[c + 2], wp[(size_t)(c + 2) * (2 * DCH)], a2);
        a3 = fmaf(apr[c + 3], wp[(size_t)(c + 3) * (2 * DCH)], a3);
    }
    red[cp][o] = (a0 + a1) + (a2 + a3);
    __syncthreads();
    if (t < 256) {
        int hd2 = half * 256 + t;
        out[(size_t)b * DCH + hd2] = bkv[DCH + hd2] + red[0][t] + red[1][t];
    }
}

// ---------------------------------------------------------------------------
extern "C" void kernel_launch(void* const* d_in, const int* in_sizes, int n_in,
                              void* d_out, int out_size, void* d_ws, size_t ws_size,
                              hipStream_t stream) {
    const float* x   = (const float*)d_in[0];   // (64, 512, 32, 32)
    const float* q   = (const float*)d_in[1];   // (1, 8, 1, 64)
    const float* Wkv = (const float*)d_in[2];   // (512, 1024)
    const float* bkv = (const float*)d_in[3];   // (1024,)
    float* out = (float*)d_out;                 // (64, 512)

    float* ws    = (float*)d_ws;
    float* wqT   = ws;                                         // 512*8
    float* bias  = wqT + DCH * NH;                             // 8*1024
    float* apart = bias + NH * NPOS;                           // 16 MiB
    float* mz    = apart + (size_t)NSPLIT * BATCH * NH * DCH;  // 16*64*16

    hipLaunchKernelGGL(k_prep,  dim3(6),             dim3(256), 0, stream, q, Wkv, bkv, wqT, bias);
    hipLaunchKernelGGL(k_flash, dim3(NSPLIT, BATCH), dim3(512), 0, stream, x, wqT, bias, apart, mz);
    hipLaunchKernelGGL(k_comb,  dim3(BATCH, 2),      dim3(512), 0, stream, apart, mz, Wkv, bkv, out);
}